// Round 4
// baseline (126.149 us; speedup 1.0000x reference)
//
#include <hip/hip_runtime.h>
#include <stdint.h>

#define NROWS 8192
#define DIM 128
#define ROWB 256       // bytes per e16 row
#define NIBLK 32       // i-blocks of 256 rows
#define NCHUNK 64      // j-chunks of 128 cols
#define MARGIN 0.5f

typedef short short8 __attribute__((ext_vector_type(8)));   // 8 bf16 (4 VGPRs)
typedef float f32x4 __attribute__((ext_vector_type(4)));
typedef int   int4v __attribute__((ext_vector_type(4)));

#define GLDS16(g, l) __builtin_amdgcn_global_load_lds( \
    (const __attribute__((address_space(1))) unsigned int*)(g), \
    (__attribute__((address_space(3))) unsigned int*)(l), 16, 0, 0)

static __device__ __forceinline__ unsigned short f2bf(float f) {
    union { float f; unsigned u; } x; x.f = f;
    unsigned u = x.u;
    return (unsigned short)((u + 0x7FFFu + ((u >> 16) & 1u)) >> 16);  // RNE
}

// ---------------------------------------------------------------------------
// prep: bf16 copy of embeds, c_j = sq_j + 512 (f32 exact); zeroes out[0].
// ---------------------------------------------------------------------------
__global__ __launch_bounds__(256) void prep(const float* __restrict__ emb,
                                            unsigned short* __restrict__ e16,
                                            float* __restrict__ cbuf,
                                            float* __restrict__ out) {
    const int lane = threadIdx.x & 63;
    const int row = blockIdx.x * 4 + (threadIdx.x >> 6);
    const float2 v = reinterpret_cast<const float2*>(emb + row * DIM)[lane];
    float sq = v.x * v.x + v.y * v.y;
#pragma unroll
    for (int m = 1; m < 64; m <<= 1) sq += __shfl_xor(sq, m, 64);
    const unsigned pack = ((unsigned)f2bf(v.y) << 16) | (unsigned)f2bf(v.x);
    *reinterpret_cast<unsigned*>(e16 + row * DIM + lane * 2) = pack;
    if (lane == 0) cbuf[row] = sq + 512.0f;
    if (blockIdx.x == 0 && threadIdx.x == 0) out[0] = 0.0f;
}

// ---------------------------------------------------------------------------
// mine: fused Gram-GEMM + batch-hard mining, LDS-staged j-tiles.
// Grid: 32 i-blocks (256 rows) x 64 j-chunks (128 cols) = 2048 blocks.
// Block: 4 waves; wave owns 4 i-tiles of 16 (bfrag in regs all kernel).
// j-chunk processed in 4 stages of 32 j (8KB tile), double-buffered LDS
// (16KB total -> high blocks/CU). global_load_lds linear dest; both-sides
// XOR swizzle (chunk ^= row&15 on global source and on ds_read address)
// -> conflict-free LDS reads.
// Accumulator init = -c_j/2 so final s = dot - c_j/2 < 0:
//   hardest positive = max d2 -> MAX u32 bits of s
//   hardest negative = min d2 -> MIN u32 bits of s
// Candidate = (s_bits & ~8191) | j; sentinels 0 / 0xFFFFFFFF.
// ---------------------------------------------------------------------------
__global__ __launch_bounds__(256) void mine(const unsigned short* __restrict__ e16,
                                            const float* __restrict__ cbuf,
                                            const int* __restrict__ labels,
                                            unsigned* __restrict__ pos_part,
                                            unsigned* __restrict__ neg_part) {
    __shared__ char smem[2][8192];
    const int tid  = threadIdx.x;
    const int wave = tid >> 6;
    const int lane = tid & 63;
    const int l15  = lane & 15;
    const int lhi  = lane >> 4;
    const int iblk = blockIdx.x & (NIBLK - 1);
    const int cblk = blockIdx.x / NIBLK;
    const int ibase = iblk * 256 + wave * 64;
    const char* e8 = (const char*)e16;
    const int jcbase = cblk * 128;

    // Prologue stage of j-rows [0,32) (issued first; overlaps bfrag loads).
    {
        const char* gs = e8 + (size_t)(jcbase + wave * 8) * ROWB;
        char* lb = &smem[0][wave * 2048];
#pragma unroll
        for (int q = 0; q < 2; ++q) {
            const int r = wave * 8 + q * 4 + lhi;     // row within stage's 32
            const int ch = l15 ^ (r & 15);            // pre-swizzled src chunk
            GLDS16(gs + (q * 4 + lhi) * ROWB + ch * 16, lb + q * 1024);
        }
    }

    // B operand (i side): registers for the whole kernel.
    short8 bfrag[4][4];
    int labi[4];
#pragma unroll
    for (int it = 0; it < 4; ++it) {
        const int row = ibase + it * 16 + l15;
#pragma unroll
        for (int ks = 0; ks < 4; ++ks)
            bfrag[it][ks] = *reinterpret_cast<const short8*>(e8 + (size_t)row * ROWB + ks * 64 + lhi * 16);
        labi[it] = labels[row];
    }

    unsigned bp[4] = {0u, 0u, 0u, 0u};
    unsigned bn[4] = {0xFFFFFFFFu, 0xFFFFFFFFu, 0xFFFFFFFFu, 0xFFFFFFFFu};

    __syncthreads();   // prologue tile landed (barrier drains vmcnt)

#pragma unroll
    for (int st = 0; st < 4; ++st) {
        if (st < 3) {  // issue next-stage prefetch before compute
            const char* gs = e8 + (size_t)(jcbase + (st + 1) * 32 + wave * 8) * ROWB;
            char* lb = &smem[(st + 1) & 1][wave * 2048];
#pragma unroll
            for (int q = 0; q < 2; ++q) {
                const int r = wave * 8 + q * 4 + lhi;
                const int ch = l15 ^ (r & 15);
                GLDS16(gs + (q * 4 + lhi) * ROWB + ch * 16, lb + q * 1024);
            }
        }
        const char* buf = smem[st & 1];
#pragma unroll
        for (int sub = 0; sub < 2; ++sub) {
            const int jb = jcbase + st * 32 + sub * 16;
            const int4v labj = *reinterpret_cast<const int4v*>(labels + jb + lhi * 4);
            const f32x4 c4   = *reinterpret_cast<const f32x4*>(cbuf + jb + lhi * 4);
            const f32x4 cinit = c4 * -0.5f;

            short8 af[4];
#pragma unroll
            for (int ks = 0; ks < 4; ++ks)
                af[ks] = *reinterpret_cast<const short8*>(
                    buf + (sub * 16 + l15) * ROWB + ((ks * 4 + lhi) ^ l15) * 16);

            f32x4 acc[4];
#pragma unroll
            for (int it = 0; it < 4; ++it)
                acc[it] = __builtin_amdgcn_mfma_f32_16x16x32_bf16(af[0], bfrag[it][0], cinit, 0, 0, 0);
#pragma unroll
            for (int ks = 1; ks < 4; ++ks)
#pragma unroll
                for (int it = 0; it < 4; ++it)
                    acc[it] = __builtin_amdgcn_mfma_f32_16x16x32_bf16(af[ks], bfrag[it][ks], acc[it], 0, 0, 0);

            const int j0 = jb + lhi * 4;
#pragma unroll
            for (int it = 0; it < 4; ++it) {
#pragma unroll
                for (int r = 0; r < 4; ++r) {
                    union { float f; unsigned u; } cv; cv.f = acc[it][r];
                    const unsigned cand = (cv.u & 0xFFFFE000u) | (unsigned)(j0 + r);
                    const bool eq = (labj[r] == labi[it]);
                    const unsigned psel = eq ? cand : 0u;
                    const unsigned nsel = eq ? 0xFFFFFFFFu : cand;
                    bp[it] = bp[it] > psel ? bp[it] : psel;
                    bn[it] = bn[it] < nsel ? bn[it] : nsel;
                }
            }
        }
        __syncthreads();   // drains prefetch (vmcnt) + protects buf reuse
    }

    // cross-lane: lanes {l, l^16, l^32, l^48} share the same i
#pragma unroll
    for (int it = 0; it < 4; ++it) {
        unsigned p = bp[it], n = bn[it];
        unsigned o;
        o = (unsigned)__shfl_xor((int)p, 16, 64); p = p > o ? p : o;
        o = (unsigned)__shfl_xor((int)p, 32, 64); p = p > o ? p : o;
        o = (unsigned)__shfl_xor((int)n, 16, 64); n = n < o ? n : o;
        o = (unsigned)__shfl_xor((int)n, 32, 64); n = n < o ? n : o;
        if (lane < 16) {
            pos_part[cblk * NROWS + ibase + it * 16 + lane] = p;
            neg_part[cblk * NROWS + ibase + it * 16 + lane] = n;
        }
    }
}

// ---------------------------------------------------------------------------
// lossk: one row per wave; lane <-> chunk (64), two interleaved butterflies
// (max for pos, min for neg), exact f32 ap/an from mined indices, block
// reduce, one scaled atomicAdd per block into out[0].
// ---------------------------------------------------------------------------
__global__ __launch_bounds__(256) void lossk(const float* __restrict__ emb,
                                             const unsigned* __restrict__ pos_part,
                                             const unsigned* __restrict__ neg_part,
                                             float* __restrict__ out) {
    __shared__ float wsum[4];
    const int tid = threadIdx.x, lane = tid & 63, wave = tid >> 6;
    const int i = blockIdx.x * 4 + wave;          // 0..8191
    unsigned p = pos_part[lane * NROWS + i];
    unsigned n = neg_part[lane * NROWS + i];
#pragma unroll
    for (int m = 1; m < 64; m <<= 1) {
        const unsigned op = (unsigned)__shfl_xor((int)p, m, 64);
        const unsigned on = (unsigned)__shfl_xor((int)n, m, 64);
        p = p > op ? p : op;
        n = n < on ? n : on;
    }
    const int jp = (int)(p & 8191u);
    const int jn = (int)(n & 8191u);
    const float2 a = reinterpret_cast<const float2*>(emb + (size_t)i  * DIM)[lane];
    const float2 b = reinterpret_cast<const float2*>(emb + (size_t)jp * DIM)[lane];
    const float2 c = reinterpret_cast<const float2*>(emb + (size_t)jn * DIM)[lane];
    float dx = a.x - b.x, dy = a.y - b.y;
    const float ap = dx * dx + dy * dy;
    dx = a.x - c.x; dy = a.y - c.y;
    const float an = dx * dx + dy * dy;
    float s = ap - an;
#pragma unroll
    for (int m = 1; m < 64; m <<= 1) s += __shfl_xor(s, m, 64);
    if (lane == 0) wsum[wave] = fmaxf(s + MARGIN, 0.f);
    __syncthreads();
    if (tid == 0)
        atomicAdd(out, (wsum[0] + wsum[1] + wsum[2] + wsum[3]) * (1.0f / (float)NROWS));
}

// ---------------------------------------------------------------------------
extern "C" void kernel_launch(void* const* d_in, const int* in_sizes, int n_in,
                              void* d_out, int out_size, void* d_ws, size_t ws_size,
                              hipStream_t stream) {
    const float* emb   = (const float*)d_in[0];
    const int* labels  = (const int*)d_in[1];
    float* out = (float*)d_out;
    char* ws = (char*)d_ws;

    unsigned short* e16 = (unsigned short*)ws;                         // 2 MB
    float* cbuf         = (float*)(ws + (size_t)2097152);              // 32 KB
    unsigned* pos_part  = (unsigned*)(ws + (size_t)2097152 + 32768);   // 2 MB
    unsigned* neg_part  = pos_part + (size_t)NCHUNK * NROWS;           // 2 MB

    prep<<<2048, 256, 0, stream>>>(emb, e16, cbuf, out);
    mine<<<NIBLK * NCHUNK, 256, 0, stream>>>(e16, cbuf, labels, pos_part, neg_part);
    lossk<<<2048, 256, 0, stream>>>(emb, pos_part, neg_part, out);
}

// Round 5
// 94.387 us; speedup vs baseline: 1.3365x; 1.3365x over previous
//
#include <hip/hip_runtime.h>
#include <stdint.h>

#define NROWS 8192
#define DIM 128
#define ROWB 256       // bytes per e16 row
#define NIBLK 64       // i-blocks of 128 rows
#define NCHUNK 32      // j-chunks of 256 cols
#define MARGIN 0.5f

typedef short short8 __attribute__((ext_vector_type(8)));   // 8 bf16 (4 VGPRs)
typedef float f32x4 __attribute__((ext_vector_type(4)));
typedef int   int4v __attribute__((ext_vector_type(4)));

#define GLDS16(g, l) __builtin_amdgcn_global_load_lds( \
    (const __attribute__((address_space(1))) unsigned int*)(g), \
    (__attribute__((address_space(3))) unsigned int*)(l), 16, 0, 0)

static __device__ __forceinline__ unsigned short f2bf(float f) {
    union { float f; unsigned u; } x; x.f = f;
    unsigned u = x.u;
    return (unsigned short)((u + 0x7FFFu + ((u >> 16) & 1u)) >> 16);  // RNE
}

// ---------------------------------------------------------------------------
// prep: bf16 copy of embeds, c_j = sq_j + 512; init pos/neg atomic targets
// (pos=0, neg=~0) and out[0]=0. One wave per row.
// ---------------------------------------------------------------------------
__global__ __launch_bounds__(256) void prep(const float* __restrict__ emb,
                                            unsigned short* __restrict__ e16,
                                            float* __restrict__ cbuf,
                                            unsigned* __restrict__ pos,
                                            unsigned* __restrict__ neg,
                                            float* __restrict__ out) {
    const int lane = threadIdx.x & 63;
    const int row = blockIdx.x * 4 + (threadIdx.x >> 6);
    const float2 v = reinterpret_cast<const float2*>(emb + row * DIM)[lane];
    float sq = v.x * v.x + v.y * v.y;
#pragma unroll
    for (int m = 1; m < 64; m <<= 1) sq += __shfl_xor(sq, m, 64);
    const unsigned pack = ((unsigned)f2bf(v.y) << 16) | (unsigned)f2bf(v.x);
    *reinterpret_cast<unsigned*>(e16 + row * DIM + lane * 2) = pack;
    if (lane == 0) cbuf[row] = sq + 512.0f;
    if (lane == 1) pos[row] = 0u;
    if (lane == 2) neg[row] = 0xFFFFFFFFu;
    if (blockIdx.x == 0 && threadIdx.x == 0) out[0] = 0.0f;
}

// ---------------------------------------------------------------------------
// mine: fused Gram-GEMM + batch-hard mining.
// Grid: 64 i-blocks (128 rows) x 32 j-chunks (256 cols) = 2048 blocks.
// Block: 8 waves (512 thr); each wave owns ONE 16-row i-tile (bfrag in regs).
// j processed in 4 stages of 64 rows (16KB), double-buffered LDS (32KB).
// global_load_lds linear dest; both-sides XOR swizzle (chunk ^= row&15 on the
// global SOURCE and on the ds_read address) -> conflict-free (verified 0).
// Accumulator init = -c_j/2 so final s = dot - c_j/2 < 0:
//   hardest positive = max d2 -> MAX u32 bits ; hardest negative -> MIN u32.
// Candidate = (s_bits & ~8191) | j. Block result published via
// atomicMax(pos[i]) / atomicMin(neg[i]) — 8192 distinct addresses.
// ---------------------------------------------------------------------------
__global__ __launch_bounds__(512, 6) void mine(const unsigned short* __restrict__ e16,
                                               const float* __restrict__ cbuf,
                                               const int* __restrict__ labels,
                                               unsigned* __restrict__ pos,
                                               unsigned* __restrict__ neg) {
    __shared__ char smem[2][16384];
    const int tid  = threadIdx.x;
    const int wave = tid >> 6;
    const int lane = tid & 63;
    const int l15  = lane & 15;
    const int lhi  = lane >> 4;
    const int iblk = blockIdx.x & (NIBLK - 1);
    const int cblk = blockIdx.x / NIBLK;
    const int irow = iblk * 128 + wave * 16 + l15;
    const char* e8 = (const char*)e16;
    const int jc = cblk * 256;

    // Prologue: stage j-rows [0,64) into buf 0 (overlaps bfrag loads).
    {
        const char* gs = e8 + (size_t)jc * ROWB;
        char* lb = smem[0];
#pragma unroll
        for (int q = 0; q < 2; ++q) {
            const int r = q * 32 + (tid >> 4);        // row 0..63 in stage
            const int d = tid & 15;                   // linear dest chunk
            const int g = d ^ (r & 15);               // pre-swizzled src chunk
            GLDS16(gs + (size_t)r * ROWB + g * 16, lb + q * 8192 + tid * 16);
        }
    }

    // B operand (i side): registers for the whole kernel.
    short8 bfrag[4];
#pragma unroll
    for (int ks = 0; ks < 4; ++ks)
        bfrag[ks] = *reinterpret_cast<const short8*>(e8 + (size_t)irow * ROWB + (ks * 4 + lhi) * 16);
    const int labi = labels[irow];

    unsigned bp = 0u, bn = 0xFFFFFFFFu;

    __syncthreads();   // prologue tile landed (barrier drains vmcnt)

#pragma unroll
    for (int st = 0; st < 4; ++st) {
        if (st < 3) {  // issue next-stage prefetch before compute
            const char* gs = e8 + (size_t)(jc + (st + 1) * 64) * ROWB;
            char* lb = smem[(st + 1) & 1];
#pragma unroll
            for (int q = 0; q < 2; ++q) {
                const int r = q * 32 + (tid >> 4);
                const int d = tid & 15;
                const int g = d ^ (r & 15);
                GLDS16(gs + (size_t)r * ROWB + g * 16, lb + q * 8192 + tid * 16);
            }
        }
        const char* buf = smem[st & 1];
#pragma unroll
        for (int jt = 0; jt < 4; ++jt) {
            const int jb = jc + st * 64 + jt * 16;
            const int4v labj = *reinterpret_cast<const int4v*>(labels + jb + lhi * 4);
            const f32x4 c4   = *reinterpret_cast<const f32x4*>(cbuf + jb + lhi * 4);
            const f32x4 cinit = c4 * -0.5f;

            short8 af[4];
#pragma unroll
            for (int ks = 0; ks < 4; ++ks)
                af[ks] = *reinterpret_cast<const short8*>(
                    buf + (jt * 16 + l15) * ROWB + (((ks * 4 + lhi) ^ l15) * 16));

            f32x4 acc = __builtin_amdgcn_mfma_f32_16x16x32_bf16(af[0], bfrag[0], cinit, 0, 0, 0);
#pragma unroll
            for (int ks = 1; ks < 4; ++ks)
                acc = __builtin_amdgcn_mfma_f32_16x16x32_bf16(af[ks], bfrag[ks], acc, 0, 0, 0);

            const int j0 = jb + lhi * 4;
#pragma unroll
            for (int r = 0; r < 4; ++r) {
                union { float f; unsigned u; } cv; cv.f = acc[r];
                const unsigned cand = (cv.u & 0xFFFFE000u) | (unsigned)(j0 + r);
                const bool eq = (labj[r] == labi);
                const unsigned psel = eq ? cand : 0u;
                const unsigned nsel = eq ? 0xFFFFFFFFu : cand;
                bp = bp > psel ? bp : psel;
                bn = bn < nsel ? bn : nsel;
            }
        }
        __syncthreads();   // drains prefetch (vmcnt) + protects buf reuse
    }

    // cross-lane: lanes {l, l^16, l^32, l^48} share the same i (= l15)
    {
        unsigned o;
        o = (unsigned)__shfl_xor((int)bp, 16, 64); bp = bp > o ? bp : o;
        o = (unsigned)__shfl_xor((int)bp, 32, 64); bp = bp > o ? bp : o;
        o = (unsigned)__shfl_xor((int)bn, 16, 64); bn = bn < o ? bn : o;
        o = (unsigned)__shfl_xor((int)bn, 32, 64); bn = bn < o ? bn : o;
    }
    if (lane < 16) {
        const int i = iblk * 128 + wave * 16 + lane;
        atomicMax(&pos[i], bp);
        atomicMin(&neg[i], bn);
    }
}

// ---------------------------------------------------------------------------
// lossk: one row per wave; uniform read of mined indices, exact f32 ap/an,
// butterfly sum, per-block partial into bsum (distinct addresses).
// ---------------------------------------------------------------------------
__global__ __launch_bounds__(256) void lossk(const float* __restrict__ emb,
                                             const unsigned* __restrict__ pos,
                                             const unsigned* __restrict__ neg,
                                             float* __restrict__ bsum) {
    __shared__ float wsum[4];
    const int tid = threadIdx.x, lane = tid & 63, wave = tid >> 6;
    const int i = blockIdx.x * 4 + wave;          // 0..8191
    const int jp = (int)(pos[i] & 8191u);
    const int jn = (int)(neg[i] & 8191u);
    const float2 a = reinterpret_cast<const float2*>(emb + (size_t)i  * DIM)[lane];
    const float2 b = reinterpret_cast<const float2*>(emb + (size_t)jp * DIM)[lane];
    const float2 c = reinterpret_cast<const float2*>(emb + (size_t)jn * DIM)[lane];
    float dx = a.x - b.x, dy = a.y - b.y;
    const float ap = dx * dx + dy * dy;
    dx = a.x - c.x; dy = a.y - c.y;
    const float an = dx * dx + dy * dy;
    float s = ap - an;
#pragma unroll
    for (int m = 1; m < 64; m <<= 1) s += __shfl_xor(s, m, 64);
    if (lane == 0) wsum[wave] = fmaxf(s + MARGIN, 0.f);
    __syncthreads();
    if (tid == 0) bsum[blockIdx.x] = wsum[0] + wsum[1] + wsum[2] + wsum[3];
}

// ---------------------------------------------------------------------------
// fin: reduce 2048 block sums -> mean. One block.
// ---------------------------------------------------------------------------
__global__ __launch_bounds__(256) void fin(const float* __restrict__ bsum,
                                           float* __restrict__ out) {
    __shared__ float wsum[4];
    const int tid = threadIdx.x, lane = tid & 63, wave = tid >> 6;
    float s = 0.f;
#pragma unroll
    for (int k = 0; k < 8; ++k) s += bsum[tid + k * 256];
#pragma unroll
    for (int m = 1; m < 64; m <<= 1) s += __shfl_xor(s, m, 64);
    if (lane == 0) wsum[wave] = s;
    __syncthreads();
    if (tid == 0) out[0] = (wsum[0] + wsum[1] + wsum[2] + wsum[3]) * (1.0f / (float)NROWS);
}

// ---------------------------------------------------------------------------
extern "C" void kernel_launch(void* const* d_in, const int* in_sizes, int n_in,
                              void* d_out, int out_size, void* d_ws, size_t ws_size,
                              hipStream_t stream) {
    const float* emb   = (const float*)d_in[0];
    const int* labels  = (const int*)d_in[1];
    float* out = (float*)d_out;
    char* ws = (char*)d_ws;

    unsigned short* e16 = (unsigned short*)ws;                         // 2 MB
    float* cbuf         = (float*)(ws + (size_t)2097152);              // 32 KB
    unsigned* pos       = (unsigned*)(ws + (size_t)2097152 + 32768);   // 32 KB
    unsigned* neg       = pos + NROWS;                                 // 32 KB
    float* bsum         = (float*)(neg + NROWS);                       // 8 KB

    prep<<<2048, 256, 0, stream>>>(emb, e16, cbuf, pos, neg, out);
    mine<<<NIBLK * NCHUNK, 512, 0, stream>>>(e16, cbuf, labels, pos, neg);
    lossk<<<2048, 256, 0, stream>>>(emb, pos, neg, bsum);
    fin<<<1, 256, 0, stream>>>(bsum, out);
}

// Round 6
// 92.455 us; speedup vs baseline: 1.3644x; 1.0209x over previous
//
#include <hip/hip_runtime.h>
#include <stdint.h>

#define NROWS 8192
#define DIM 128
#define ROWB 256       // bytes per e16 row
#define NIBLK 64       // i-blocks of 128 rows
#define NCHUNK 32      // j-chunks of 256 cols
#define MARGIN 0.5f

typedef short short8 __attribute__((ext_vector_type(8)));   // 8 bf16 (4 VGPRs)
typedef float f32x4 __attribute__((ext_vector_type(4)));
typedef int   int4v __attribute__((ext_vector_type(4)));

#define GLDS16(g, l) __builtin_amdgcn_global_load_lds( \
    (const __attribute__((address_space(1))) unsigned int*)(g), \
    (__attribute__((address_space(3))) unsigned int*)(l), 16, 0, 0)

static __device__ __forceinline__ unsigned short f2bf(float f) {
    union { float f; unsigned u; } x; x.f = f;
    unsigned u = x.u;
    return (unsigned short)((u + 0x7FFFu + ((u >> 16) & 1u)) >> 16);  // RNE
}

// ---------------------------------------------------------------------------
// prep: bf16 copy of embeds, c_j = sq_j + 512; init pos/neg atomic targets
// (pos=0, neg=~0) and out[0]=0. One wave per row.
// ---------------------------------------------------------------------------
__global__ __launch_bounds__(256) void prep(const float* __restrict__ emb,
                                            unsigned short* __restrict__ e16,
                                            float* __restrict__ cbuf,
                                            unsigned* __restrict__ pos,
                                            unsigned* __restrict__ neg,
                                            float* __restrict__ out) {
    const int lane = threadIdx.x & 63;
    const int row = blockIdx.x * 4 + (threadIdx.x >> 6);
    const float2 v = reinterpret_cast<const float2*>(emb + row * DIM)[lane];
    float sq = v.x * v.x + v.y * v.y;
#pragma unroll
    for (int m = 1; m < 64; m <<= 1) sq += __shfl_xor(sq, m, 64);
    const unsigned pack = ((unsigned)f2bf(v.y) << 16) | (unsigned)f2bf(v.x);
    *reinterpret_cast<unsigned*>(e16 + row * DIM + lane * 2) = pack;
    if (lane == 0) cbuf[row] = sq + 512.0f;
    if (lane == 1) pos[row] = 0u;
    if (lane == 2) neg[row] = 0xFFFFFFFFu;
    if (blockIdx.x == 0 && threadIdx.x == 0) out[0] = 0.0f;
}

// ---------------------------------------------------------------------------
// mine: fused Gram-GEMM + batch-hard mining.
// Grid: 64 i-blocks (128 rows) x 32 j-chunks (256 cols) = 2048 blocks
// (8 blocks/CU of work; ~4-5 resident -> cross-block TLP hides barriers).
// Block: 4 waves (256 thr); wave owns TWO 16-row i-tiles (bfrag in regs).
// j processed in 4 stages of 64 rows (16KB), double-buffered LDS (32KB).
// global_load_lds linear dest; both-sides XOR swizzle (chunk ^= row&15 on
// the global SOURCE and on the ds_read address) -> conflict-free (verified).
// Accumulator init = -c_j/2 so final s = dot - c_j/2 < 0:
//   hardest positive = max d2 -> MAX u32 bits ; hardest negative -> MIN u32.
// Candidate = (s_bits & ~8191) | j. Result published via atomicMax(pos[i]) /
// atomicMin(neg[i]) — 8192 distinct addresses, 32 contenders each.
// ---------------------------------------------------------------------------
__global__ __launch_bounds__(256, 4) void mine(const unsigned short* __restrict__ e16,
                                               const float* __restrict__ cbuf,
                                               const int* __restrict__ labels,
                                               unsigned* __restrict__ pos,
                                               unsigned* __restrict__ neg) {
    __shared__ char smem[2][16384];
    const int tid  = threadIdx.x;
    const int wave = tid >> 6;
    const int lane = tid & 63;
    const int l15  = lane & 15;
    const int lhi  = lane >> 4;
    const int iblk = blockIdx.x & (NIBLK - 1);
    const int cblk = blockIdx.x / NIBLK;
    const int ibase = iblk * 128 + wave * 32;
    const char* e8 = (const char*)e16;
    const int jc = cblk * 256;

    // Staging geometry (256 threads, 64 rows x 256B per stage):
    //   dest  = lb + q*4096 + tid*16            (linear: row q*16+(tid>>4))
    //   src   = gs + r*ROWB + (d ^ (r&15))*16,  r&15 == tid>>4 (q*16 ≡ 0 mod 16)
    const int srow = tid >> 4;                       // 0..15
    const int gsw  = ((tid & 15) ^ srow) * 16;       // pre-swizzled src byte

    // Prologue: stage j-rows [0,64) into buf 0 (overlaps bfrag loads).
    {
        const char* gs = e8 + (size_t)jc * ROWB;
        char* lb = smem[0];
#pragma unroll
        for (int q = 0; q < 4; ++q)
            GLDS16(gs + (size_t)(q * 16 + srow) * ROWB + gsw, lb + q * 4096 + tid * 16);
    }

    // B operand (i side): registers for the whole kernel.
    short8 bfrag[2][4];
    int labi[2];
#pragma unroll
    for (int it = 0; it < 2; ++it) {
        const int row = ibase + it * 16 + l15;
#pragma unroll
        for (int ks = 0; ks < 4; ++ks)
            bfrag[it][ks] = *reinterpret_cast<const short8*>(e8 + (size_t)row * ROWB + (ks * 4 + lhi) * 16);
        labi[it] = labels[row];
    }

    // Per-lane constant ds_read offsets (swizzled), folded to immediates.
    int dsoff[4];
#pragma unroll
    for (int ks = 0; ks < 4; ++ks)
        dsoff[ks] = l15 * ROWB + (((ks * 4 + lhi) ^ l15) * 16);

    unsigned bp[2] = {0u, 0u};
    unsigned bn[2] = {0xFFFFFFFFu, 0xFFFFFFFFu};

    __syncthreads();   // prologue tile landed (barrier drains vmcnt)

#pragma unroll
    for (int st = 0; st < 4; ++st) {
        if (st < 3) {  // issue next-stage prefetch before compute
            const char* gs = e8 + (size_t)(jc + (st + 1) * 64) * ROWB;
            char* lb = smem[(st + 1) & 1];
#pragma unroll
            for (int q = 0; q < 4; ++q)
                GLDS16(gs + (size_t)(q * 16 + srow) * ROWB + gsw, lb + q * 4096 + tid * 16);
        }
        // Hoisted per-stage label/cinit loads (batched, latency amortized).
        int4v labj_s[4];
        f32x4 cin_s[4];
#pragma unroll
        for (int jt = 0; jt < 4; ++jt) {
            const int jb = jc + st * 64 + jt * 16;
            labj_s[jt] = *reinterpret_cast<const int4v*>(labels + jb + lhi * 4);
            cin_s[jt]  = *reinterpret_cast<const f32x4*>(cbuf + jb + lhi * 4) * -0.5f;
        }
        const char* buf = smem[st & 1];
#pragma unroll
        for (int jt = 0; jt < 4; ++jt) {
            short8 af[4];
#pragma unroll
            for (int ks = 0; ks < 4; ++ks)
                af[ks] = *reinterpret_cast<const short8*>(buf + jt * 4096 + dsoff[ks]);

            f32x4 acc[2];
#pragma unroll
            for (int it = 0; it < 2; ++it)
                acc[it] = __builtin_amdgcn_mfma_f32_16x16x32_bf16(af[0], bfrag[it][0], cin_s[jt], 0, 0, 0);
#pragma unroll
            for (int ks = 1; ks < 4; ++ks)
#pragma unroll
                for (int it = 0; it < 2; ++it)
                    acc[it] = __builtin_amdgcn_mfma_f32_16x16x32_bf16(af[ks], bfrag[it][ks], acc[it], 0, 0, 0);

            const int j0 = jc + st * 64 + jt * 16 + lhi * 4;
#pragma unroll
            for (int it = 0; it < 2; ++it) {
#pragma unroll
                for (int r = 0; r < 4; ++r) {
                    union { float f; unsigned u; } cv; cv.f = acc[it][r];
                    const unsigned cand = (cv.u & 0xFFFFE000u) | (unsigned)(j0 + r);
                    const bool eq = (labj_s[jt][r] == labi[it]);
                    const unsigned psel = eq ? cand : 0u;            // vcc cndmask
                    const unsigned nsel = eq ? 0xFFFFFFFFu : cand;   // vcc cndmask
                    bp[it] = bp[it] > psel ? bp[it] : psel;
                    bn[it] = bn[it] < nsel ? bn[it] : nsel;
                }
            }
        }
        __syncthreads();   // drains prefetch (vmcnt) + protects buf reuse
    }

    // cross-lane: lanes {l, l^16, l^32, l^48} share the same i (= l15)
#pragma unroll
    for (int it = 0; it < 2; ++it) {
        unsigned o;
        o = (unsigned)__shfl_xor((int)bp[it], 16, 64); bp[it] = bp[it] > o ? bp[it] : o;
        o = (unsigned)__shfl_xor((int)bp[it], 32, 64); bp[it] = bp[it] > o ? bp[it] : o;
        o = (unsigned)__shfl_xor((int)bn[it], 16, 64); bn[it] = bn[it] < o ? bn[it] : o;
        o = (unsigned)__shfl_xor((int)bn[it], 32, 64); bn[it] = bn[it] < o ? bn[it] : o;
    }
    if (lane < 32) {  // lanes 0-15 publish it=0 (i=ibase+lane); 16-31 it=1
        const int it = lane >> 4;
        const int i = ibase + lane;   // ibase + it*16 + (lane&15)
        atomicMax(&pos[i], bp[it]);
        atomicMin(&neg[i], bn[it]);
    }
}

// ---------------------------------------------------------------------------
// lossk: one row per wave; uniform read of mined indices, exact f32 ap/an,
// butterfly sum, per-block partial into bsum (distinct addresses).
// ---------------------------------------------------------------------------
__global__ __launch_bounds__(256) void lossk(const float* __restrict__ emb,
                                             const unsigned* __restrict__ pos,
                                             const unsigned* __restrict__ neg,
                                             float* __restrict__ bsum) {
    __shared__ float wsum[4];
    const int tid = threadIdx.x, lane = tid & 63, wave = tid >> 6;
    const int i = blockIdx.x * 4 + wave;          // 0..8191
    const int jp = (int)(pos[i] & 8191u);
    const int jn = (int)(neg[i] & 8191u);
    const float2 a = reinterpret_cast<const float2*>(emb + (size_t)i  * DIM)[lane];
    const float2 b = reinterpret_cast<const float2*>(emb + (size_t)jp * DIM)[lane];
    const float2 c = reinterpret_cast<const float2*>(emb + (size_t)jn * DIM)[lane];
    float dx = a.x - b.x, dy = a.y - b.y;
    const float ap = dx * dx + dy * dy;
    dx = a.x - c.x; dy = a.y - c.y;
    const float an = dx * dx + dy * dy;
    float s = ap - an;
#pragma unroll
    for (int m = 1; m < 64; m <<= 1) s += __shfl_xor(s, m, 64);
    if (lane == 0) wsum[wave] = fmaxf(s + MARGIN, 0.f);
    __syncthreads();
    if (tid == 0) bsum[blockIdx.x] = wsum[0] + wsum[1] + wsum[2] + wsum[3];
}

// ---------------------------------------------------------------------------
// fin: reduce 2048 block sums -> mean. One block.
// ---------------------------------------------------------------------------
__global__ __launch_bounds__(256) void fin(const float* __restrict__ bsum,
                                           float* __restrict__ out) {
    __shared__ float wsum[4];
    const int tid = threadIdx.x, lane = tid & 63, wave = tid >> 6;
    float s = 0.f;
#pragma unroll
    for (int k = 0; k < 8; ++k) s += bsum[tid + k * 256];
#pragma unroll
    for (int m = 1; m < 64; m <<= 1) s += __shfl_xor(s, m, 64);
    if (lane == 0) wsum[wave] = s;
    __syncthreads();
    if (tid == 0) out[0] = (wsum[0] + wsum[1] + wsum[2] + wsum[3]) * (1.0f / (float)NROWS);
}

// ---------------------------------------------------------------------------
extern "C" void kernel_launch(void* const* d_in, const int* in_sizes, int n_in,
                              void* d_out, int out_size, void* d_ws, size_t ws_size,
                              hipStream_t stream) {
    const float* emb   = (const float*)d_in[0];
    const int* labels  = (const int*)d_in[1];
    float* out = (float*)d_out;
    char* ws = (char*)d_ws;

    unsigned short* e16 = (unsigned short*)ws;                         // 2 MB
    float* cbuf         = (float*)(ws + (size_t)2097152);              // 32 KB
    unsigned* pos       = (unsigned*)(ws + (size_t)2097152 + 32768);   // 32 KB
    unsigned* neg       = pos + NROWS;                                 // 32 KB
    float* bsum         = (float*)(neg + NROWS);                       // 8 KB

    prep<<<2048, 256, 0, stream>>>(emb, e16, cbuf, pos, neg, out);
    mine<<<NIBLK * NCHUNK, 256, 0, stream>>>(e16, cbuf, labels, pos, neg);
    lossk<<<2048, 256, 0, stream>>>(emb, pos, neg, bsum);
    fin<<<1, 256, 0, stream>>>(bsum, out);
}

// Round 7
// 90.359 us; speedup vs baseline: 1.3961x; 1.0232x over previous
//
#include <hip/hip_runtime.h>
#include <stdint.h>

#define NROWS 8192
#define DIM 128
#define MARGIN 0.5f

typedef short short8 __attribute__((ext_vector_type(8)));   // 8 bf16 (4 VGPRs)
typedef float f32x4 __attribute__((ext_vector_type(4)));
typedef int   int4v __attribute__((ext_vector_type(4)));

static __device__ __forceinline__ unsigned short f2bf(float f) {
    union { float f; unsigned u; } x; x.f = f;
    unsigned u = x.u;
    return (unsigned short)((u + 0x7FFFu + ((u >> 16) & 1u)) >> 16);  // RNE
}

// ---------------------------------------------------------------------------
// prep: build the FRAGMENT-ORDERED bf16 matrix
//   efrag[tile=row>>4][ks=col>>5][lane=((col>>3)&3)*16 + (row&15)][byte=(col&7)*2]
// so that in mine, every MFMA A/B fragment load is ONE coalesced dwordx4:
//   frag(tile,ks) = efrag + tile*4096 + ks*1024 + lane*16.
// Also c_j = sq_j + 512 (f32 exact), pos/neg atomic init, out[0]=0.
// One wave per row; lane d handles cols 2d,2d+1 (one 4B store).
// ---------------------------------------------------------------------------
__global__ __launch_bounds__(256) void prep(const float* __restrict__ emb,
                                            char* __restrict__ efrag,
                                            float* __restrict__ cbuf,
                                            unsigned* __restrict__ pos,
                                            unsigned* __restrict__ neg,
                                            float* __restrict__ out) {
    const int d = threadIdx.x & 63;
    const int row = blockIdx.x * 4 + (threadIdx.x >> 6);
    const float2 v = reinterpret_cast<const float2*>(emb + row * DIM)[d];
    float sq = v.x * v.x + v.y * v.y;
#pragma unroll
    for (int m = 1; m < 64; m <<= 1) sq += __shfl_xor(sq, m, 64);
    const unsigned pack = ((unsigned)f2bf(v.y) << 16) | (unsigned)f2bf(v.x);
    char* dst = efrag + (size_t)(row >> 4) * 4096 + (d >> 4) * 1024
              + ((((d >> 2) & 3) * 16 + (row & 15)) * 16) + (d & 3) * 4;
    *reinterpret_cast<unsigned*>(dst) = pack;
    if (d == 0) cbuf[row] = sq + 512.0f;
    if (d == 1) pos[row] = 0u;
    if (d == 2) neg[row] = 0xFFFFFFFFu;
    if (blockIdx.x == 0 && threadIdx.x == 0) out[0] = 0.0f;
}

// ---------------------------------------------------------------------------
// mine: fused Gram-GEMM + batch-hard mining. NO LDS, NO barriers.
// Grid: 32 i-blocks (256 rows) x 32 j-chunks (256 cols) = 1024 blocks
// (exactly 4 blocks/CU, all co-resident in one generation; waves free-run).
// Block: 4 waves; wave owns FOUR 16-row i-tiles (bfrag in regs, coalesced
// loads from efrag). All 4 waves share the j-chunk -> af re-reads L1-hit.
// Per j-tile: 4 coalesced dwordx4 af loads + 16 MFMA + selects.
// Accumulator init = -c_j/2 so final s = dot - c_j/2 < 0:
//   hardest positive = max d2 -> MAX u32 bits ; hardest negative -> MIN u32.
// Candidate = (s_bits & ~8191) | j  (v_and_or_b32). Publish via
// atomicMax(pos[i]) / atomicMin(neg[i]) — 8192 distinct addresses.
// ---------------------------------------------------------------------------
__global__ __launch_bounds__(256, 4) void mine(const char* __restrict__ efrag,
                                               const float* __restrict__ cbuf,
                                               const int* __restrict__ labels,
                                               unsigned* __restrict__ pos,
                                               unsigned* __restrict__ neg) {
    const int tid  = threadIdx.x;
    const int wave = tid >> 6;
    const int lane = tid & 63;
    const int l15  = lane & 15;
    const int lhi  = lane >> 4;
    const int iblk = blockIdx.x & 31;
    const int cblk = blockIdx.x >> 5;
    const int ibase = iblk * 256 + wave * 64;

    // B operand (i side): 4 tiles, coalesced fragment loads, regs all kernel.
    short8 bfrag[4][4];
    int labi[4];
#pragma unroll
    for (int it = 0; it < 4; ++it) {
        const char* bt = efrag + (size_t)((ibase >> 4) + it) * 4096 + lane * 16;
#pragma unroll
        for (int ks = 0; ks < 4; ++ks)
            bfrag[it][ks] = *reinterpret_cast<const short8*>(bt + ks * 1024);
        labi[it] = labels[ibase + it * 16 + l15];
    }

    unsigned bp[4] = {0u, 0u, 0u, 0u};
    unsigned bn[4] = {0xFFFFFFFFu, 0xFFFFFFFFu, 0xFFFFFFFFu, 0xFFFFFFFFu};

    const int jc = cblk * 256;
    const char* aj = efrag + (size_t)(cblk * 16) * 4096 + lane * 16;

#pragma unroll 2
    for (int jt = 0; jt < 16; ++jt) {
        const int jb = jc + jt * 16;
        const int4v labj = *reinterpret_cast<const int4v*>(labels + jb + lhi * 4);
        const f32x4 cinit = *reinterpret_cast<const f32x4*>(cbuf + jb + lhi * 4) * -0.5f;
        const char* at = aj + (size_t)jt * 4096;

        // ks in two halves to cap af register pressure.
        const short8 af0 = *reinterpret_cast<const short8*>(at);
        const short8 af1 = *reinterpret_cast<const short8*>(at + 1024);
        f32x4 acc[4];
#pragma unroll
        for (int it = 0; it < 4; ++it)
            acc[it] = __builtin_amdgcn_mfma_f32_16x16x32_bf16(af0, bfrag[it][0], cinit, 0, 0, 0);
#pragma unroll
        for (int it = 0; it < 4; ++it)
            acc[it] = __builtin_amdgcn_mfma_f32_16x16x32_bf16(af1, bfrag[it][1], acc[it], 0, 0, 0);
        const short8 af2 = *reinterpret_cast<const short8*>(at + 2048);
        const short8 af3 = *reinterpret_cast<const short8*>(at + 3072);
#pragma unroll
        for (int it = 0; it < 4; ++it)
            acc[it] = __builtin_amdgcn_mfma_f32_16x16x32_bf16(af2, bfrag[it][2], acc[it], 0, 0, 0);
#pragma unroll
        for (int it = 0; it < 4; ++it)
            acc[it] = __builtin_amdgcn_mfma_f32_16x16x32_bf16(af3, bfrag[it][3], acc[it], 0, 0, 0);

        const int jv = jb + lhi * 4;        // this lane's j for r=0 (then +r)
#pragma unroll
        for (int it = 0; it < 4; ++it) {
#pragma unroll
            for (int r = 0; r < 4; ++r) {
                union { float f; unsigned u; } cv; cv.f = acc[it][r];
                const unsigned cand = (cv.u & 0xFFFFE000u) | (unsigned)(jv + r);
                const bool eq = (labj[r] == labi[it]);
                const unsigned psel = eq ? cand : 0u;            // vcc cndmask
                const unsigned nsel = eq ? 0xFFFFFFFFu : cand;   // vcc cndmask
                bp[it] = bp[it] > psel ? bp[it] : psel;
                bn[it] = bn[it] < nsel ? bn[it] : nsel;
            }
        }
    }

    // cross-lane: lanes {l, l^16, l^32, l^48} share the same i (= l15)
#pragma unroll
    for (int it = 0; it < 4; ++it) {
        unsigned o;
        o = (unsigned)__shfl_xor((int)bp[it], 16, 64); bp[it] = bp[it] > o ? bp[it] : o;
        o = (unsigned)__shfl_xor((int)bp[it], 32, 64); bp[it] = bp[it] > o ? bp[it] : o;
        o = (unsigned)__shfl_xor((int)bn[it], 16, 64); bn[it] = bn[it] < o ? bn[it] : o;
        o = (unsigned)__shfl_xor((int)bn[it], 32, 64); bn[it] = bn[it] < o ? bn[it] : o;
        if (lane < 16) {
            const int i = ibase + it * 16 + lane;
            atomicMax(&pos[i], bp[it]);
            atomicMin(&neg[i], bn[it]);
        }
    }
}

// ---------------------------------------------------------------------------
// lossk: one row per wave; uniform read of mined indices, exact f32 ap/an,
// butterfly sum, per-block partial into bsum (distinct addresses).
// ---------------------------------------------------------------------------
__global__ __launch_bounds__(256) void lossk(const float* __restrict__ emb,
                                             const unsigned* __restrict__ pos,
                                             const unsigned* __restrict__ neg,
                                             float* __restrict__ bsum) {
    __shared__ float wsum[4];
    const int tid = threadIdx.x, lane = tid & 63, wave = tid >> 6;
    const int i = blockIdx.x * 4 + wave;          // 0..8191
    const int jp = (int)(pos[i] & 8191u);
    const int jn = (int)(neg[i] & 8191u);
    const float2 a = reinterpret_cast<const float2*>(emb + (size_t)i  * DIM)[lane];
    const float2 b = reinterpret_cast<const float2*>(emb + (size_t)jp * DIM)[lane];
    const float2 c = reinterpret_cast<const float2*>(emb + (size_t)jn * DIM)[lane];
    float dx = a.x - b.x, dy = a.y - b.y;
    const float ap = dx * dx + dy * dy;
    dx = a.x - c.x; dy = a.y - c.y;
    const float an = dx * dx + dy * dy;
    float s = ap - an;
#pragma unroll
    for (int m = 1; m < 64; m <<= 1) s += __shfl_xor(s, m, 64);
    if (lane == 0) wsum[wave] = fmaxf(s + MARGIN, 0.f);
    __syncthreads();
    if (tid == 0) bsum[blockIdx.x] = wsum[0] + wsum[1] + wsum[2] + wsum[3];
}

// ---------------------------------------------------------------------------
// fin: reduce 2048 block sums -> mean. One block.
// ---------------------------------------------------------------------------
__global__ __launch_bounds__(256) void fin(const float* __restrict__ bsum,
                                           float* __restrict__ out) {
    __shared__ float wsum[4];
    const int tid = threadIdx.x, lane = tid & 63, wave = tid >> 6;
    float s = 0.f;
#pragma unroll
    for (int k = 0; k < 8; ++k) s += bsum[tid + k * 256];
#pragma unroll
    for (int m = 1; m < 64; m <<= 1) s += __shfl_xor(s, m, 64);
    if (lane == 0) wsum[wave] = s;
    __syncthreads();
    if (tid == 0) out[0] = (wsum[0] + wsum[1] + wsum[2] + wsum[3]) * (1.0f / (float)NROWS);
}

// ---------------------------------------------------------------------------
extern "C" void kernel_launch(void* const* d_in, const int* in_sizes, int n_in,
                              void* d_out, int out_size, void* d_ws, size_t ws_size,
                              hipStream_t stream) {
    const float* emb   = (const float*)d_in[0];
    const int* labels  = (const int*)d_in[1];
    float* out = (float*)d_out;
    char* ws = (char*)d_ws;

    char* efrag    = ws;                                            // 2 MB
    float* cbuf    = (float*)(ws + (size_t)2097152);                // 32 KB
    unsigned* pos  = (unsigned*)(ws + (size_t)2097152 + 32768);     // 32 KB
    unsigned* neg  = pos + NROWS;                                   // 32 KB
    float* bsum    = (float*)(neg + NROWS);                         // 8 KB

    prep<<<2048, 256, 0, stream>>>(emb, efrag, cbuf, pos, neg, out);
    mine<<<1024, 256, 0, stream>>>(efrag, cbuf, labels, pos, neg);
    lossk<<<2048, 256, 0, stream>>>(emb, pos, neg, bsum);
    fin<<<1, 256, 0, stream>>>(bsum, out);
}